// Round 1
// baseline (356.052 us; speedup 1.0000x reference)
//
#include <hip/hip_runtime.h>
#include <hip/hip_bf16.h>

#define NN 500000
#define ED 128
// H1=256, H2=128, H3=64

typedef unsigned short ushort_t;
typedef __attribute__((ext_vector_type(8))) __bf16 bf16x8;
typedef __attribute__((ext_vector_type(4))) float f32x4;

__device__ inline ushort_t f2bf(float f) {
  union { float f; unsigned u; } x; x.f = f;
  return (ushort_t)((x.u + 0x7FFFu + ((x.u >> 16) & 1u)) >> 16);
}
__device__ inline float bf2f(ushort_t h) {
  union { unsigned u; float f; } x; x.u = ((unsigned)h) << 16; return x.f;
}
__device__ inline float lrelu(float v) { return v > 0.f ? v : 0.01f * v; }

// ---------------- K_transpose: weights fp32 -> bf16, n-major (B^T) layout ----------------
// W1T': [256 n][pitch 136] <- W1 rows 256..383 ; W2T: [128][264] ; W3T: [64][136]
__global__ __launch_bounds__(256) void k_transpose(
    const float* __restrict__ W1, const float* __restrict__ W2,
    const float* __restrict__ W3,
    ushort_t* __restrict__ w1t, ushort_t* __restrict__ w2t,
    ushort_t* __restrict__ w3t)
{
  int i = blockIdx.x * 256 + threadIdx.x;   // grid covers 73728 exactly
  if (i < 32768) {
    int n = i & 255, k = i >> 8;            // n<256, k<128
    w1t[n * 136 + k] = f2bf(W1[(256 + k) * 256 + n]);
  } else if (i < 65536) {
    int j = i - 32768;
    int n = j & 127, k = j >> 7;            // n<128, k<256
    w2t[n * 264 + k] = f2bf(W2[k * 128 + n]);
  } else {
    int j = i - 65536;
    int n = j & 63, k = j >> 6;             // n<64, k<128
    w3t[n * 136 + k] = f2bf(W3[k * 64 + n]);
  }
}

// ---------------- K_colmax: masked per-column max over N rows ----------------
__global__ __launch_bounds__(256) void k_colmax(
    const float* __restrict__ enc, const int* __restrict__ cs,
    float* mu_in, float* mu_not)
{
  __shared__ float4 s_in[256], s_not[256];
  const int tid = threadIdx.x;
  const int c4 = tid & 31;    // float4-column 0..31
  const int rs = tid >> 5;    // row slice 0..7
  const long base = (long)blockIdx.x * 496;
  float4 mi = {0.f, 0.f, 0.f, 0.f}, mn = {0.f, 0.f, 0.f, 0.f};
  const float4* e4 = (const float4*)enc;
  for (int it = 0; it < 62; ++it) {
    long r = base + rs + 8L * it;
    if (r < NN) {
      float4 v = e4[r * 32 + c4];
      bool ins = cs[r] > 0;
      mi.x = fmaxf(mi.x, ins ? v.x : 0.f); mi.y = fmaxf(mi.y, ins ? v.y : 0.f);
      mi.z = fmaxf(mi.z, ins ? v.z : 0.f); mi.w = fmaxf(mi.w, ins ? v.w : 0.f);
      mn.x = fmaxf(mn.x, ins ? 0.f : v.x); mn.y = fmaxf(mn.y, ins ? 0.f : v.y);
      mn.z = fmaxf(mn.z, ins ? 0.f : v.z); mn.w = fmaxf(mn.w, ins ? 0.f : v.w);
    }
  }
  s_in[tid] = mi; s_not[tid] = mn;
  __syncthreads();
  if (tid < 32) {
    for (int j = 1; j < 8; ++j) {
      float4 a = s_in[j * 32 + tid], b = s_not[j * 32 + tid];
      mi.x = fmaxf(mi.x, a.x); mi.y = fmaxf(mi.y, a.y);
      mi.z = fmaxf(mi.z, a.z); mi.w = fmaxf(mi.w, a.w);
      mn.x = fmaxf(mn.x, b.x); mn.y = fmaxf(mn.y, b.y);
      mn.z = fmaxf(mn.z, b.z); mn.w = fmaxf(mn.w, b.w);
    }
    // maxima are >= 0 so int-bit compare == float compare
    atomicMax((int*)&mu_in[4 * tid + 0], __float_as_int(mi.x));
    atomicMax((int*)&mu_in[4 * tid + 1], __float_as_int(mi.y));
    atomicMax((int*)&mu_in[4 * tid + 2], __float_as_int(mi.z));
    atomicMax((int*)&mu_in[4 * tid + 3], __float_as_int(mi.w));
    atomicMax((int*)&mu_not[4 * tid + 0], __float_as_int(mn.x));
    atomicMax((int*)&mu_not[4 * tid + 1], __float_as_int(mn.y));
    atomicMax((int*)&mu_not[4 * tid + 2], __float_as_int(mn.z));
    atomicMax((int*)&mu_not[4 * tid + 3], __float_as_int(mn.w));
  }
}

// ---------------- K_cvec: fold mu_in/mu_not through W1 rows 0..255 into c[256] (fp32 exact) ----
__global__ __launch_bounds__(256) void k_cvec(
    const float* __restrict__ W1, const float* __restrict__ b1,
    const float* __restrict__ mu_in, const float* __restrict__ mu_not,
    float* __restrict__ cvec)
{
  const int j = threadIdx.x;  // 0..255
  float c = b1[j];
  #pragma unroll 4
  for (int e = 0; e < 128; ++e) {
    c += mu_in[e]  * W1[e * 256 + j];          // relu(mu)=mu: maxima >= 0
    c += mu_not[e] * W1[(128 + e) * 256 + j];
  }
  cvec[j] = c;
}

// ---------------- K_mlp: fused 4-layer MLP with bf16 MFMA ----------------
// 512 threads = 8 waves; wave handles 16 rows; block handles 128 rows.
__global__ __launch_bounds__(512) void k_mlp(
    const float* __restrict__ enc,
    const ushort_t* __restrict__ w1t, const ushort_t* __restrict__ w2t,
    const ushort_t* __restrict__ w3t,
    const float* __restrict__ cvec, const float* __restrict__ b2,
    const float* __restrict__ b3, const float* __restrict__ W4,
    const float* __restrict__ b4, float* __restrict__ logits)
{
  __shared__ alignas(16) ushort_t sW[34816];     // 69632 B, reused W1T'/W2T/W3T
  __shared__ float sC[512];                      // c[256] | b2[128] | b3[64] | W4[64]
  __shared__ alignas(16) ushort_t sB[8][4224];   // per-wave bounce, pitch-padded

  const int tid = threadIdx.x;
  const int wave = tid >> 6, lane = tid & 63;
  const int lr = lane & 15, lg = lane >> 4;
  ushort_t* myB = sB[wave];

  if (tid < 256) sC[tid] = cvec[tid];
  else if (tid < 384) sC[tid] = b2[tid - 256];
  else if (tid < 448) sC[tid] = b3[tid - 384];
  else sC[tid] = W4[tid - 448];

  { // stage W1T' (69632 B)
    const float4* s = (const float4*)w1t; float4* d = (float4*)sW;
    for (int i = tid; i < 4352; i += 512) d[i] = s[i];
  }
  __syncthreads();

  const int r = blockIdx.x * 128 + wave * 16 + lr;
  const int rg = min(r, NN - 1);
  const float* erow = enc + (size_t)rg * ED;

  // ---- L1: [16,128] @ [128,256] ----
  bf16x8 a1[4];
  #pragma unroll
  for (int kb = 0; kb < 4; ++kb) {
    const int k0 = kb * 32 + lg * 8;
    float4 f0 = *(const float4*)(erow + k0);
    float4 f1 = *(const float4*)(erow + k0 + 4);
    bf16x8 a;
    a[0] = (__bf16)f0.x; a[1] = (__bf16)f0.y; a[2] = (__bf16)f0.z; a[3] = (__bf16)f0.w;
    a[4] = (__bf16)f1.x; a[5] = (__bf16)f1.y; a[6] = (__bf16)f1.z; a[7] = (__bf16)f1.w;
    a1[kb] = a;
  }
  f32x4 acc[16];
  #pragma unroll
  for (int nt = 0; nt < 16; ++nt) acc[nt] = (f32x4){0.f, 0.f, 0.f, 0.f};
  #pragma unroll
  for (int nt = 0; nt < 16; ++nt) {
    const ushort_t* bp = sW + (lr + 16 * nt) * 136 + lg * 8;
    #pragma unroll
    for (int kb = 0; kb < 4; ++kb) {
      bf16x8 b = *(const bf16x8*)(bp + kb * 32);
      acc[nt] = __builtin_amdgcn_mfma_f32_16x16x32_bf16(a1[kb], b, acc[nt], 0, 0, 0);
    }
  }
  // epilogue: +c, leaky, bf16 -> bounce h1 [16][pitch 264]
  #pragma unroll
  for (int nt = 0; nt < 16; ++nt) {
    const int col = lr + 16 * nt;
    const float bias = sC[col];
    #pragma unroll
    for (int i = 0; i < 4; ++i) {
      float v = lrelu(acc[nt][i] + bias);
      myB[(4 * lg + i) * 264 + col] = f2bf(v);
    }
  }
  __syncthreads();

  { // stage W2T (67584 B)
    const float4* s = (const float4*)w2t; float4* d = (float4*)sW;
    for (int i = tid; i < 4224; i += 512) d[i] = s[i];
  }
  __syncthreads();

  // ---- L2: [16,256] @ [256,128] ----
  bf16x8 a2[8];
  #pragma unroll
  for (int kb = 0; kb < 8; ++kb)
    a2[kb] = *(const bf16x8*)(myB + lr * 264 + kb * 32 + lg * 8);
  f32x4 acc2[8];
  #pragma unroll
  for (int nt = 0; nt < 8; ++nt) acc2[nt] = (f32x4){0.f, 0.f, 0.f, 0.f};
  #pragma unroll
  for (int nt = 0; nt < 8; ++nt) {
    const ushort_t* bp = sW + (lr + 16 * nt) * 264 + lg * 8;
    #pragma unroll
    for (int kb = 0; kb < 8; ++kb) {
      bf16x8 b = *(const bf16x8*)(bp + kb * 32);
      acc2[nt] = __builtin_amdgcn_mfma_f32_16x16x32_bf16(a2[kb], b, acc2[nt], 0, 0, 0);
    }
  }
  #pragma unroll
  for (int nt = 0; nt < 8; ++nt) {
    const int col = lr + 16 * nt;
    const float bias = sC[256 + col];
    #pragma unroll
    for (int i = 0; i < 4; ++i) {
      float v = lrelu(acc2[nt][i] + bias);
      myB[(4 * lg + i) * 136 + col] = f2bf(v);   // h2 [16][pitch 136]
    }
  }
  __syncthreads();

  { // stage W3T (17408 B)
    const float4* s = (const float4*)w3t; float4* d = (float4*)sW;
    for (int i = tid; i < 1088; i += 512) d[i] = s[i];
  }
  __syncthreads();

  // ---- L3: [16,128] @ [128,64] ----
  bf16x8 a3[4];
  #pragma unroll
  for (int kb = 0; kb < 4; ++kb)
    a3[kb] = *(const bf16x8*)(myB + lr * 136 + kb * 32 + lg * 8);
  f32x4 acc3[4];
  #pragma unroll
  for (int nt = 0; nt < 4; ++nt) acc3[nt] = (f32x4){0.f, 0.f, 0.f, 0.f};
  #pragma unroll
  for (int nt = 0; nt < 4; ++nt) {
    const ushort_t* bp = sW + (lr + 16 * nt) * 136 + lg * 8;
    #pragma unroll
    for (int kb = 0; kb < 4; ++kb) {
      bf16x8 b = *(const bf16x8*)(bp + kb * 32);
      acc3[nt] = __builtin_amdgcn_mfma_f32_16x16x32_bf16(a3[kb], b, acc3[nt], 0, 0, 0);
    }
  }
  #pragma unroll
  for (int nt = 0; nt < 4; ++nt) {
    const int col = lr + 16 * nt;
    const float bias = sC[384 + col];
    #pragma unroll
    for (int i = 0; i < 4; ++i) {
      float v = lrelu(acc3[nt][i] + bias);
      myB[(4 * lg + i) * 72 + col] = f2bf(v);    // h3 [16][pitch 72]
    }
  }

  // ---- L4: [16,64] @ [64,1]  (dot product + 4-way shuffle reduce) ----
  float part = 0.f;
  const int k0 = lg * 16;
  #pragma unroll
  for (int j = 0; j < 16; ++j)
    part += bf2f(myB[lr * 72 + k0 + j]) * sC[448 + k0 + j];
  part += __shfl_xor(part, 16);
  part += __shfl_xor(part, 32);
  if (lg == 0 && r < NN) logits[r] = part + b4[0];
}

// ---------------- softmax (no max-subtraction: logits are ~0.01 scale) ----------------
__global__ __launch_bounds__(256) void k_expsum(const float* __restrict__ logits,
                                                float* __restrict__ psum)
{
  const int tid = threadIdx.x;
  float s = 0.f;
  for (int i = blockIdx.x * 256 + tid; i < NN; i += 256 * 256)
    s += expf(logits[i]);
  #pragma unroll
  for (int off = 1; off < 64; off <<= 1) s += __shfl_xor(s, off);
  __shared__ float sr[4];
  if ((tid & 63) == 0) sr[tid >> 6] = s;
  __syncthreads();
  if (tid == 0) psum[blockIdx.x] = sr[0] + sr[1] + sr[2] + sr[3];
}

__global__ __launch_bounds__(256) void k_finalsum(const float* __restrict__ psum,
                                                  float* __restrict__ scal)
{
  const int tid = threadIdx.x;
  float s = psum[tid];
  #pragma unroll
  for (int off = 1; off < 64; off <<= 1) s += __shfl_xor(s, off);
  __shared__ float sr[4];
  if ((tid & 63) == 0) sr[tid >> 6] = s;
  __syncthreads();
  if (tid == 0) scal[0] = 1.f / (sr[0] + sr[1] + sr[2] + sr[3]);
}

__global__ __launch_bounds__(256) void k_norm(const float* __restrict__ logits,
                                              const float* __restrict__ scal,
                                              float* __restrict__ out)
{
  const float inv = scal[0];
  const int i = blockIdx.x * 256 + threadIdx.x;
  if (i < NN) out[i] = expf(logits[i]) * inv;
}

extern "C" void kernel_launch(void* const* d_in, const int* in_sizes, int n_in,
                              void* d_out, int out_size, void* d_ws, size_t ws_size,
                              hipStream_t stream) {
  const float* enc = (const float*)d_in[0];
  const int*   cs  = (const int*)d_in[1];
  const float* W1  = (const float*)d_in[2];
  const float* b1  = (const float*)d_in[3];
  const float* W2  = (const float*)d_in[4];
  const float* b2  = (const float*)d_in[5];
  const float* W3  = (const float*)d_in[6];
  const float* b3  = (const float*)d_in[7];
  const float* W4  = (const float*)d_in[8];
  const float* b4  = (const float*)d_in[9];
  float* out = (float*)d_out;

  char* ws = (char*)d_ws;
  float*    mu_in  = (float*)(ws + 0);        // 512 B
  float*    mu_not = (float*)(ws + 512);      // 512 B
  float*    cvec   = (float*)(ws + 1024);     // 1 KB
  float*    psum   = (float*)(ws + 2048);     // 1 KB
  float*    scal   = (float*)(ws + 3072);     // 4 B
  ushort_t* w1t    = (ushort_t*)(ws + 4096);     // 256*136*2 = 69632
  ushort_t* w2t    = (ushort_t*)(ws + 73728);    // 128*264*2 = 67584
  ushort_t* w3t    = (ushort_t*)(ws + 141312);   // 64*136*2  = 17408
  float*    logits = (float*)(ws + 158720);      // 2 MB

  hipMemsetAsync(ws, 0, 1024, stream);  // zero mu_in/mu_not (identity: masked max >= 0)

  k_transpose<<<dim3(288), dim3(256), 0, stream>>>(W1, W2, W3, w1t, w2t, w3t);
  k_colmax<<<dim3(1009), dim3(256), 0, stream>>>(enc, cs, mu_in, mu_not);
  k_cvec<<<dim3(1), dim3(256), 0, stream>>>(W1, b1, mu_in, mu_not, cvec);
  k_mlp<<<dim3(3907), dim3(512), 0, stream>>>(enc, w1t, w2t, w3t, cvec, b2, b3,
                                              W4, b4, logits);
  k_expsum<<<dim3(256), dim3(256), 0, stream>>>(logits, psum);
  k_finalsum<<<dim3(1), dim3(256), 0, stream>>>(psum, scal);
  k_norm<<<dim3(1954), dim3(256), 0, stream>>>(logits, scal, out);
}